// Round 4
// baseline (499.507 us; speedup 1.0000x reference)
//
#include <hip/hip_runtime.h>

#define LN_EPS 1e-5f
#define ROWS 2

typedef float v2f __attribute__((ext_vector_type(2)));

__device__ __forceinline__ float fast_rcp(float x) {
    return __builtin_amdgcn_rcpf(x);
}

__device__ __forceinline__ v2f ld2(const float* p) {
    return *reinterpret_cast<const v2f*>(p);
}

__device__ __forceinline__ v2f pk_fma(v2f a, v2f b, v2f c) {
    return __builtin_elementwise_fma(a, b, c);
}

__device__ __forceinline__ v2f splat(float s) {
    v2f r = {s, s};
    return r;
}

__device__ __forceinline__ float silu_f(float x) {
    // x * sigmoid(x); exp overflow -> inf -> rcp -> 0 (correct limit)
    return x * fast_rcp(1.0f + __expf(-x));
}

__device__ __forceinline__ v2f silu2(v2f a) {
    v2f r;
    r.x = silu_f(a.x);
    r.y = silu_f(a.y);
    return r;
}

__device__ __forceinline__ float tanh_f(float x) {
    float ax = fabsf(x);
    float t = __expf(-2.0f * ax);
    float r = (1.0f - t) * fast_rcp(1.0f + t);
    return copysignf(r, x);
}

__device__ __forceinline__ float softplus_f(float x) {
    float e = __expf(-fabsf(x));
    return fmaxf(x, 0.0f) + __logf(1.0f + e);
}

// Two-row expert, weight loads shared across rows.
// w1: (16,24) row-major, w2: (24,16) row-major.
// Accumulates: acc[r][j] = acc[r][j]*accscale? -> we do: if FIRST, acc = scale*out; else acc += scale*out.
template <bool FIRST>
__device__ __forceinline__ void expert_pk(const float xv[ROWS][16],
                                          const float* __restrict__ w1,
                                          const float* __restrict__ b1,
                                          const float* __restrict__ g,
                                          const float* __restrict__ bn,
                                          const float* __restrict__ w2,
                                          const float* __restrict__ b2,
                                          const float scale[ROWS],
                                          v2f acc[ROWS][8]) {
    v2f hh[ROWS][12];
#pragma unroll
    for (int j = 0; j < 12; ++j) {
        v2f b = ld2(b1 + 2 * j);
#pragma unroll
        for (int r = 0; r < ROWS; ++r) hh[r][j] = b;
    }
#pragma unroll
    for (int k = 0; k < 16; ++k) {
#pragma unroll
        for (int j = 0; j < 12; ++j) {
            v2f w = ld2(w1 + k * 24 + 2 * j);
#pragma unroll
            for (int r = 0; r < ROWS; ++r)
                hh[r][j] = pk_fma(splat(xv[r][k]), w, hh[r][j]);
        }
    }
    float mu[ROWS], rstd[ROWS];
#pragma unroll
    for (int r = 0; r < ROWS; ++r) {
        v2f sv = hh[r][0];
#pragma unroll
        for (int j = 1; j < 12; ++j) sv = sv + hh[r][j];
        mu[r] = (sv.x + sv.y) * (1.0f / 24.0f);
        v2f muv = splat(mu[r]);
        v2f vv = {0.0f, 0.0f};
#pragma unroll
        for (int j = 0; j < 12; ++j) {
            v2f d = hh[r][j] - muv;
            vv = pk_fma(d, d, vv);
        }
        rstd[r] = rsqrtf(fmaf(vv.x + vv.y, 1.0f / 24.0f, LN_EPS));
    }
#pragma unroll
    for (int j = 0; j < 12; ++j) {
        v2f gv = ld2(g + 2 * j);
        v2f bv = ld2(bn + 2 * j);
#pragma unroll
        for (int r = 0; r < ROWS; ++r) {
            v2f n = pk_fma((hh[r][j] - splat(mu[r])) * splat(rstd[r]), gv, bv);
            hh[r][j] = silu2(n);
        }
    }
    // out = silu(h @ w2 + b2); acc (+)= scale * out
    v2f ov[ROWS][8];
#pragma unroll
    for (int j = 0; j < 8; ++j) {
        v2f b = ld2(b2 + 2 * j);
#pragma unroll
        for (int r = 0; r < ROWS; ++r) ov[r][j] = b;
    }
#pragma unroll
    for (int k = 0; k < 24; ++k) {
        float hk[ROWS];
#pragma unroll
        for (int r = 0; r < ROWS; ++r)
            hk[r] = (k & 1) ? hh[r][k >> 1].y : hh[r][k >> 1].x;
#pragma unroll
        for (int j = 0; j < 8; ++j) {
            v2f w = ld2(w2 + k * 16 + 2 * j);
#pragma unroll
            for (int r = 0; r < ROWS; ++r)
                ov[r][j] = pk_fma(splat(hk[r]), w, ov[r][j]);
        }
    }
#pragma unroll
    for (int j = 0; j < 8; ++j)
#pragma unroll
        for (int r = 0; r < ROWS; ++r) {
            v2f s = silu2(ov[r][j]);
            if (FIRST)
                acc[r][j] = splat(scale[r]) * s;
            else
                acc[r][j] = pk_fma(splat(scale[r]), s, acc[r][j]);
        }
}

__global__ __launch_bounds__(256, 2) void moe_fused_kernel(
    const float* __restrict__ x,
    const float* __restrict__ gw1, const float* __restrict__ gb1,
    const float* __restrict__ gw2, const float* __restrict__ gb2,
    const float* __restrict__ e1w1, const float* __restrict__ e1b1,
    const float* __restrict__ e1g, const float* __restrict__ e1bn,
    const float* __restrict__ e1w2, const float* __restrict__ e1b2,
    const float* __restrict__ e2w1, const float* __restrict__ e2b1,
    const float* __restrict__ e2g, const float* __restrict__ e2bn,
    const float* __restrict__ e2w2, const float* __restrict__ e2b2,
    const float* __restrict__ tw, const float* __restrict__ tb,
    const float* __restrict__ sw, const float* __restrict__ sb,
    const float* __restrict__ hw, const float* __restrict__ hb,
    float* __restrict__ out, int nrows) {
    int row0 = (blockIdx.x * blockDim.x + threadIdx.x) * ROWS;
    if (row0 >= nrows) return;

    // ---- load x rows (clamp OOB row to last valid; its output is masked) ----
    float xv[ROWS][16];
#pragma unroll
    for (int r = 0; r < ROWS; ++r) {
        int rr = row0 + r;
        if (rr >= nrows) rr = nrows - 1;
        const float4* xr = reinterpret_cast<const float4*>(x + (size_t)rr * 16);
#pragma unroll
        for (int i = 0; i < 4; ++i) {
            float4 v = xr[i];
            xv[r][4 * i + 0] = v.x;
            xv[r][4 * i + 1] = v.y;
            xv[r][4 * i + 2] = v.z;
            xv[r][4 * i + 3] = v.w;
        }
    }

    // ---- gate: w0 = sigmoid(l0 - l1), l = tanh(x@gw1+gb1)@gw2+gb2 ----
    v2f ga[ROWS][4];
#pragma unroll
    for (int j = 0; j < 4; ++j) {
        v2f b = ld2(gb1 + 2 * j);
#pragma unroll
        for (int r = 0; r < ROWS; ++r) ga[r][j] = b;
    }
#pragma unroll
    for (int k = 0; k < 16; ++k) {
#pragma unroll
        for (int j = 0; j < 4; ++j) {
            v2f w = ld2(gw1 + k * 8 + 2 * j);
#pragma unroll
            for (int r = 0; r < ROWS; ++r)
                ga[r][j] = pk_fma(splat(xv[r][k]), w, ga[r][j]);
        }
    }
    float gh[ROWS][8];
#pragma unroll
    for (int j = 0; j < 4; ++j)
#pragma unroll
        for (int r = 0; r < ROWS; ++r) {
            gh[r][2 * j + 0] = tanh_f(ga[r][j].x);
            gh[r][2 * j + 1] = tanh_f(ga[r][j].y);
        }
    v2f gl[ROWS];
    {
        v2f b = ld2(gb2);
#pragma unroll
        for (int r = 0; r < ROWS; ++r) gl[r] = b;
    }
#pragma unroll
    for (int k = 0; k < 8; ++k) {
        v2f w = ld2(gw2 + 2 * k);
#pragma unroll
        for (int r = 0; r < ROWS; ++r)
            gl[r] = pk_fma(splat(gh[r][k]), w, gl[r]);
    }
    float w0[ROWS], w1v[ROWS];
#pragma unroll
    for (int r = 0; r < ROWS; ++r) {
        // softmax over 2 logits == sigmoid of the difference
        w0[r] = fast_rcp(1.0f + __expf(gl[r].y - gl[r].x));
        w1v[r] = 1.0f - w0[r];
    }

    // ---- experts (h = w0*E1(x), then h += w1*E2(x); only one expert's state live) ----
    v2f h[ROWS][8];
    expert_pk<true >(xv, e1w1, e1b1, e1g, e1bn, e1w2, e1b2, w0,  h);
    expert_pk<false>(xv, e2w1, e2b1, e2g, e2bn, e2w2, e2b2, w1v, h);

    // ---- trunk: silu(h@tw+tb), tw (16,16) ----
    v2f tt[ROWS][8];
#pragma unroll
    for (int j = 0; j < 8; ++j) {
        v2f b = ld2(tb + 2 * j);
#pragma unroll
        for (int r = 0; r < ROWS; ++r) tt[r][j] = b;
    }
#pragma unroll
    for (int k = 0; k < 16; ++k) {
        float hk[ROWS];
#pragma unroll
        for (int r = 0; r < ROWS; ++r)
            hk[r] = (k & 1) ? h[r][k >> 1].y : h[r][k >> 1].x;
#pragma unroll
        for (int j = 0; j < 8; ++j) {
            v2f w = ld2(tw + k * 16 + 2 * j);
#pragma unroll
            for (int r = 0; r < ROWS; ++r)
                tt[r][j] = pk_fma(splat(hk[r]), w, tt[r][j]);
        }
    }
#pragma unroll
    for (int j = 0; j < 8; ++j)
#pragma unroll
        for (int r = 0; r < ROWS; ++r) tt[r][j] = silu2(tt[r][j]);

    // ---- heads ----
    float strain[ROWS];
    v2f hsv[ROWS];
#pragma unroll
    for (int r = 0; r < ROWS; ++r) strain[r] = sb[0];
    {
        v2f b = ld2(hb);
#pragma unroll
        for (int r = 0; r < ROWS; ++r) hsv[r] = b;
    }
#pragma unroll
    for (int k = 0; k < 16; ++k) {
        float swk = sw[k];
        v2f hwk = ld2(hw + 2 * k);
#pragma unroll
        for (int r = 0; r < ROWS; ++r) {
            float tk = (k & 1) ? tt[r][k >> 1].y : tt[r][k >> 1].x;
            strain[r] = fmaf(tk, swk, strain[r]);
            hsv[r] = pk_fma(splat(tk), hwk, hsv[r]);
        }
    }
#pragma unroll
    for (int r = 0; r < ROWS; ++r) {
        int rr = row0 + r;
        if (rr >= nrows) continue;
        float gap = softplus_f(hsv[r].y);
        size_t o = (size_t)rr * 3;
        out[o + 0] = strain[r];
        out[o + 1] = hsv[r].x;            // tensile_raw
        out[o + 2] = hsv[r].x - gap;      // yield_strength
    }
}

extern "C" void kernel_launch(void* const* d_in, const int* in_sizes, int n_in,
                              void* d_out, int out_size, void* d_ws, size_t ws_size,
                              hipStream_t stream) {
    const float* x    = (const float*)d_in[0];
    const float* gw1  = (const float*)d_in[1];
    const float* gb1  = (const float*)d_in[2];
    const float* gw2  = (const float*)d_in[3];
    const float* gb2  = (const float*)d_in[4];
    const float* e1w1 = (const float*)d_in[5];
    const float* e1b1 = (const float*)d_in[6];
    const float* e1g  = (const float*)d_in[7];
    const float* e1bn = (const float*)d_in[8];
    const float* e1w2 = (const float*)d_in[9];
    const float* e1b2 = (const float*)d_in[10];
    const float* e2w1 = (const float*)d_in[11];
    const float* e2b1 = (const float*)d_in[12];
    const float* e2g  = (const float*)d_in[13];
    const float* e2bn = (const float*)d_in[14];
    const float* e2w2 = (const float*)d_in[15];
    const float* e2b2 = (const float*)d_in[16];
    const float* tw   = (const float*)d_in[17];
    const float* tb   = (const float*)d_in[18];
    const float* sw   = (const float*)d_in[19];
    const float* sb   = (const float*)d_in[20];
    const float* hw   = (const float*)d_in[21];
    const float* hb   = (const float*)d_in[22];
    float* out = (float*)d_out;

    int nrows = in_sizes[0] / 16;
    int block = 256;
    int rows_per_block = block * ROWS;
    int grid = (nrows + rows_per_block - 1) / rows_per_block;
    moe_fused_kernel<<<grid, block, 0, stream>>>(
        x, gw1, gb1, gw2, gb2,
        e1w1, e1b1, e1g, e1bn, e1w2, e1b2,
        e2w1, e2b1, e2g, e2bn, e2w2, e2b2,
        tw, tb, sw, sb, hw, hb, out, nrows);
}

// Round 6
// 134.220 us; speedup vs baseline: 3.7216x; 3.7216x over previous
//
#include <hip/hip_runtime.h>

#define LN_EPS 1e-5f

typedef _Float16 h2 __attribute__((ext_vector_type(2)));

__device__ __forceinline__ float fast_rcp(float x) {
    return __builtin_amdgcn_rcpf(x);
}

__device__ __forceinline__ h2 cvt2(float a, float b) {
    return __builtin_bit_cast(h2, __builtin_amdgcn_cvt_pkrtz(a, b));   // v_cvt_pkrtz_f16_f32
}

__device__ __forceinline__ float dot2(h2 a, h2 b, float c) {
    return __builtin_amdgcn_fdot2(a, b, c, false);   // v_dot2_f32_f16, fp32 accum
}

__device__ __forceinline__ float silu_f(float x) {
    // x * sigmoid(x); exp overflow -> inf -> rcp -> 0 (correct limit)
    return x * fast_rcp(1.0f + __expf(-x));
}

__device__ __forceinline__ float tanh_f(float x) {
    // tanh(x) = 2*sigmoid(2x) - 1, branch-free
    float t = __expf(-2.0f * x);               // inf for very negative x -> rcp -> 0 -> -1 (correct)
    float r = fast_rcp(1.0f + t);
    return fmaf(2.0f, r, -1.0f);
}

__device__ __forceinline__ float softplus_f(float x) {
    float e = __expf(-fabsf(x));
    return fmaxf(x, 0.0f) + __logf(1.0f + e);
}

// ---- d_ws packed-weight layout (dword/h2 offsets) ----
// gw1p  [8][8]   @ 0    (64)
// gw2p  [4][2]   @ 64   (8)
// e1w1p [8][24]  @ 72   (192)
// e1w2p [12][16] @ 264  (192)
// e2w1p [8][24]  @ 456  (192)
// e2w2p [12][16] @ 648  (192)
// twp   [8][16]  @ 840  (128)
// swp   [8]      @ 968  (8)
// hwp   [8][2]   @ 976  (16)   -> total 992 h2

__global__ void pack_weights(const float* __restrict__ gw1, const float* __restrict__ gw2,
                             const float* __restrict__ e1w1, const float* __restrict__ e1w2,
                             const float* __restrict__ e2w1, const float* __restrict__ e2w2,
                             const float* __restrict__ tw, const float* __restrict__ sw,
                             const float* __restrict__ hw, h2* __restrict__ ws) {
    int t = blockIdx.x * blockDim.x + threadIdx.x;
    if (t < 64) {                                   // gw1 (16,8)
        int k2 = t >> 3, j = t & 7;
        ws[t] = cvt2(gw1[(2 * k2) * 8 + j], gw1[(2 * k2 + 1) * 8 + j]);
    } else if (t < 72) {                            // gw2 (8,2)
        int e = t - 64, k2 = e >> 1, j = e & 1;
        ws[t] = cvt2(gw2[(2 * k2) * 2 + j], gw2[(2 * k2 + 1) * 2 + j]);
    } else if (t < 264) {                           // e1w1 (16,24)
        int e = t - 72, k2 = e / 24, j = e % 24;
        ws[t] = cvt2(e1w1[(2 * k2) * 24 + j], e1w1[(2 * k2 + 1) * 24 + j]);
    } else if (t < 456) {                           // e1w2 (24,16)
        int e = t - 264, k2 = e >> 4, j = e & 15;
        ws[t] = cvt2(e1w2[(2 * k2) * 16 + j], e1w2[(2 * k2 + 1) * 16 + j]);
    } else if (t < 648) {                           // e2w1 (16,24)
        int e = t - 456, k2 = e / 24, j = e % 24;
        ws[t] = cvt2(e2w1[(2 * k2) * 24 + j], e2w1[(2 * k2 + 1) * 24 + j]);
    } else if (t < 840) {                           // e2w2 (24,16)
        int e = t - 648, k2 = e >> 4, j = e & 15;
        ws[t] = cvt2(e2w2[(2 * k2) * 16 + j], e2w2[(2 * k2 + 1) * 16 + j]);
    } else if (t < 968) {                           // tw (16,16)
        int e = t - 840, k2 = e >> 4, j = e & 15;
        ws[t] = cvt2(tw[(2 * k2) * 16 + j], tw[(2 * k2 + 1) * 16 + j]);
    } else if (t < 976) {                           // sw (16,1)
        int k2 = t - 968;
        ws[t] = cvt2(sw[2 * k2], sw[2 * k2 + 1]);
    } else if (t < 992) {                           // hw (16,2)
        int e = t - 976, k2 = e >> 1, j = e & 1;
        ws[t] = cvt2(hw[(2 * k2) * 2 + j], hw[(2 * k2 + 1) * 2 + j]);
    }
}

// One expert: h = silu(LN(x@w1 + b1)*g + bn); acc (+)= scale * silu(h@w2 + b2)
template <bool FIRST>
__device__ __forceinline__ void expert_d2(const h2 xh[8],
                                          const h2* __restrict__ wp1,   // [8][24]
                                          const float* __restrict__ b1,
                                          const float* __restrict__ g,
                                          const float* __restrict__ bn,
                                          const h2* __restrict__ wp2,   // [12][16]
                                          const float* __restrict__ b2,
                                          float scale, float* __restrict__ acc) {
    float h[24];
#pragma unroll
    for (int j = 0; j < 24; ++j) {
        float a = b1[j];
#pragma unroll
        for (int k2 = 0; k2 < 8; ++k2) a = dot2(xh[k2], wp1[k2 * 24 + j], a);
        h[j] = a;
    }
    float E = 0.0f, E2 = 0.0f;
#pragma unroll
    for (int j = 0; j < 24; ++j) {
        E += h[j];
        E2 = fmaf(h[j], h[j], E2);
    }
    float mu = E * (1.0f / 24.0f);
    float var = fmaf(E2, 1.0f / 24.0f, -mu * mu);
    float rstd = rsqrtf(var + LN_EPS);
    h2 hh[12];
#pragma unroll
    for (int j2 = 0; j2 < 12; ++j2) {
        float n0 = fmaf((h[2 * j2] - mu) * rstd, g[2 * j2], bn[2 * j2]);
        float n1 = fmaf((h[2 * j2 + 1] - mu) * rstd, g[2 * j2 + 1], bn[2 * j2 + 1]);
        hh[j2] = cvt2(silu_f(n0), silu_f(n1));
    }
#pragma unroll
    for (int j = 0; j < 16; ++j) {
        float a = b2[j];
#pragma unroll
        for (int k2 = 0; k2 < 12; ++k2) a = dot2(hh[k2], wp2[k2 * 16 + j], a);
        float s = silu_f(a);
        if (FIRST) acc[j] = scale * s;
        else       acc[j] = fmaf(scale, s, acc[j]);
    }
}

__global__ __launch_bounds__(256) void moe_fused_kernel(
    const float* __restrict__ x,
    const h2* __restrict__ ws,
    const float* __restrict__ gb1, const float* __restrict__ gb2,
    const float* __restrict__ e1b1, const float* __restrict__ e1g, const float* __restrict__ e1bn,
    const float* __restrict__ e1b2,
    const float* __restrict__ e2b1, const float* __restrict__ e2g, const float* __restrict__ e2bn,
    const float* __restrict__ e2b2,
    const float* __restrict__ tb, const float* __restrict__ sb, const float* __restrict__ hb,
    float* __restrict__ out, int nrows) {
    int row = blockIdx.x * blockDim.x + threadIdx.x;
    if (row >= nrows) return;

    const h2* gw1p  = ws;
    const h2* gw2p  = ws + 64;
    const h2* e1w1p = ws + 72;
    const h2* e1w2p = ws + 264;
    const h2* e2w1p = ws + 456;
    const h2* e2w2p = ws + 648;
    const h2* twp   = ws + 840;
    const h2* swp   = ws + 968;
    const h2* hwp   = ws + 976;

    // ---- load x row, convert to 8x half2 ----
    float xv[16];
    const float4* xr = reinterpret_cast<const float4*>(x + (size_t)row * 16);
#pragma unroll
    for (int i = 0; i < 4; ++i) {
        float4 v = xr[i];
        xv[4 * i + 0] = v.x;
        xv[4 * i + 1] = v.y;
        xv[4 * i + 2] = v.z;
        xv[4 * i + 3] = v.w;
    }
    h2 xh[8];
#pragma unroll
    for (int k2 = 0; k2 < 8; ++k2) xh[k2] = cvt2(xv[2 * k2], xv[2 * k2 + 1]);

    // ---- gate: w0 = sigmoid(l0 - l1), l = tanh(x@gw1+gb1)@gw2+gb2 ----
    float gh[8];
#pragma unroll
    for (int j = 0; j < 8; ++j) {
        float a = gb1[j];
#pragma unroll
        for (int k2 = 0; k2 < 8; ++k2) a = dot2(xh[k2], gw1p[k2 * 8 + j], a);
        gh[j] = tanh_f(a);
    }
    h2 ghh[4];
#pragma unroll
    for (int k2 = 0; k2 < 4; ++k2) ghh[k2] = cvt2(gh[2 * k2], gh[2 * k2 + 1]);
    float gl0 = gb2[0], gl1 = gb2[1];
#pragma unroll
    for (int k2 = 0; k2 < 4; ++k2) {
        gl0 = dot2(ghh[k2], gw2p[k2 * 2 + 0], gl0);
        gl1 = dot2(ghh[k2], gw2p[k2 * 2 + 1], gl1);
    }
    float w0 = fast_rcp(1.0f + __expf(gl1 - gl0));   // sigmoid(gl0-gl1)
    float w1v = 1.0f - w0;

    // ---- experts (sequential, one expert's state live at a time) ----
    float h[16];
    expert_d2<true >(xh, e1w1p, e1b1, e1g, e1bn, e1w2p, e1b2, w0,  h);
    expert_d2<false>(xh, e2w1p, e2b1, e2g, e2bn, e2w2p, e2b2, w1v, h);

    // ---- trunk: t = silu(h@tw + tb) ----
    h2 hh2[8];
#pragma unroll
    for (int k2 = 0; k2 < 8; ++k2) hh2[k2] = cvt2(h[2 * k2], h[2 * k2 + 1]);
    float t[16];
#pragma unroll
    for (int j = 0; j < 16; ++j) {
        float a = tb[j];
#pragma unroll
        for (int k2 = 0; k2 < 8; ++k2) a = dot2(hh2[k2], twp[k2 * 16 + j], a);
        t[j] = silu_f(a);
    }

    // ---- heads ----
    h2 th[8];
#pragma unroll
    for (int k2 = 0; k2 < 8; ++k2) th[k2] = cvt2(t[2 * k2], t[2 * k2 + 1]);
    float strain = sb[0], hs0 = hb[0], hs1 = hb[1];
#pragma unroll
    for (int k2 = 0; k2 < 8; ++k2) {
        strain = dot2(th[k2], swp[k2], strain);
        hs0 = dot2(th[k2], hwp[k2 * 2 + 0], hs0);
        hs1 = dot2(th[k2], hwp[k2 * 2 + 1], hs1);
    }
    float gap = softplus_f(hs1);

    size_t o = (size_t)row * 3;
    out[o + 0] = strain;
    out[o + 1] = hs0;        // tensile_raw
    out[o + 2] = hs0 - gap;  // yield_strength
}

extern "C" void kernel_launch(void* const* d_in, const int* in_sizes, int n_in,
                              void* d_out, int out_size, void* d_ws, size_t ws_size,
                              hipStream_t stream) {
    const float* x    = (const float*)d_in[0];
    const float* gw1  = (const float*)d_in[1];
    const float* gb1  = (const float*)d_in[2];
    const float* gw2  = (const float*)d_in[3];
    const float* gb2  = (const float*)d_in[4];
    const float* e1w1 = (const float*)d_in[5];
    const float* e1b1 = (const float*)d_in[6];
    const float* e1g  = (const float*)d_in[7];
    const float* e1bn = (const float*)d_in[8];
    const float* e1w2 = (const float*)d_in[9];
    const float* e1b2 = (const float*)d_in[10];
    const float* e2w1 = (const float*)d_in[11];
    const float* e2b1 = (const float*)d_in[12];
    const float* e2g  = (const float*)d_in[13];
    const float* e2bn = (const float*)d_in[14];
    const float* e2w2 = (const float*)d_in[15];
    const float* e2b2 = (const float*)d_in[16];
    const float* tw   = (const float*)d_in[17];
    const float* tb   = (const float*)d_in[18];
    const float* sw   = (const float*)d_in[19];
    const float* sb   = (const float*)d_in[20];
    const float* hw   = (const float*)d_in[21];
    const float* hb   = (const float*)d_in[22];
    float* out = (float*)d_out;
    h2* ws = (h2*)d_ws;

    // pack weights to f16 pairs (K-pair-major) into d_ws; 992 entries
    pack_weights<<<4, 256, 0, stream>>>(gw1, gw2, e1w1, e1w2, e2w1, e2w2, tw, sw, hw, ws);

    int nrows = in_sizes[0] / 16;
    int block = 256;
    int grid = (nrows + block - 1) / block;
    moe_fused_kernel<<<grid, block, 0, stream>>>(
        x, ws, gb1, gb2,
        e1b1, e1g, e1bn, e1b2,
        e2b1, e2g, e2bn, e2b2,
        tb, sb, hb, out, nrows);
}